// Round 4
// baseline (146.388 us; speedup 1.0000x reference)
//
#include <hip/hip_runtime.h>

// GCN-style symmetric-normalized CSR aggregation.
// out[d][f] = sum_{e in [row_ptr[d], row_ptr[d+1])} feat[col_idx[e]][f] * rsqrt(deg[d]*deg[col_idx[e]])
//
// Mapping: one wave (64 lanes) per destination row.
//   - 4 lane-groups of 16 lanes = 4 edge slots; 8-way unrolled => 32 edges in
//     flight per iteration. Degree dist is ~exp(16) and edge mass is
//     size-biased (~74% of edges in rows with d>16), so 32-deep MLP halves
//     the serialized latency rounds for most of the edge mass.
//   - within a group, lane k loads float4 at feature offset 4k (16 lanes x 16B
//     = full 256B row, coalesced).
//   - out-of-range slots clamp to the row's last edge (duplicate address -> L1
//     hit) with weight 0: branchless, all loads issue for max MLP.
//   - feat addressing: 32-bit byte offsets (25.6MB array) off a single 64-bit
//     base -> global_load_dwordx4 saddr+voffset form, less address VALU.
//   - cross-group reduction with __shfl_xor(16/32); group-0 lanes store (nt).

typedef float v4f __attribute__((ext_vector_type(4)));

#define UNROLL 8   // 4 lane-slots x 8 = 32 edges in flight

__global__ __launch_bounds__(256) void gcn_csr_agg(
    const int* __restrict__ row_ptr,
    const int* __restrict__ col_idx,
    const float* __restrict__ feat,
    const float* __restrict__ deg,
    float* __restrict__ out,
    int n_nodes)
{
    const int gtid = blockIdx.x * blockDim.x + threadIdx.x;
    const int row  = gtid >> 6;          // wave id = destination node
    if (row >= n_nodes) return;
    const int lane = threadIdx.x & 63;
    const int sub  = lane >> 4;          // edge slot 0..3 within wave
    const int fbyte = (lane & 15) << 4;  // feature byte offset 0,16,...,240

    const int start = row_ptr[row];
    const int end   = row_ptr[row + 1];
    const int last  = end - 1;
    const float dinv = rsqrtf(deg[row]); // deg clamped >= 1 by setup

    const char* fbase = (const char*)feat;

    v4f acc = {0.f, 0.f, 0.f, 0.f};

    for (int eb = start; eb < end; eb += 4 * UNROLL) {
        int   e[UNROLL];
        int   s[UNROLL];
        float d[UNROLL];
        v4f   f[UNROLL];

        // Stage 1: all edge-index loads issue together.
#pragma unroll
        for (int u = 0; u < UNROLL; ++u) {
            e[u] = eb + sub + 4 * u;
            const int c = min(e[u], last);   // last >= start >= 0 inside loop
            s[u] = col_idx[c];
        }

        // Stage 2: all degree + feature loads issue together (32 float4
        // gathers in flight per wave).
#pragma unroll
        for (int u = 0; u < UNROLL; ++u) {
            d[u] = deg[s[u]];
            const unsigned off = ((unsigned)s[u] << 8) + fbyte;  // s*256 + lane*16
            f[u] = *reinterpret_cast<const v4f*>(fbase + off);
        }

        // Stage 3: weights (0 for clamped duplicate slots) + accumulate.
#pragma unroll
        for (int u = 0; u < UNROLL; ++u) {
            const float w = (e[u] <= last) ? dinv * rsqrtf(d[u]) : 0.f;
            acc += w * f[u];
        }
    }

    // Reduce across the 4 edge slots (lanes differing in bits 4 and 5).
    acc.x += __shfl_xor(acc.x, 16); acc.y += __shfl_xor(acc.y, 16);
    acc.z += __shfl_xor(acc.z, 16); acc.w += __shfl_xor(acc.w, 16);
    acc.x += __shfl_xor(acc.x, 32); acc.y += __shfl_xor(acc.y, 32);
    acc.z += __shfl_xor(acc.z, 32); acc.w += __shfl_xor(acc.w, 32);

    if (sub == 0) {
        v4f* po = reinterpret_cast<v4f*>((char*)out + ((unsigned)row << 8) + fbyte);
        __builtin_nontemporal_store(acc, po);  // out is write-once: don't pollute L2
    }
}

extern "C" void kernel_launch(void* const* d_in, const int* in_sizes, int n_in,
                              void* d_out, int out_size, void* d_ws, size_t ws_size,
                              hipStream_t stream) {
    const int*   row_ptr = (const int*)d_in[0];
    const int*   col_idx = (const int*)d_in[1];
    const float* feat    = (const float*)d_in[2];
    const float* deg     = (const float*)d_in[3];
    float*       out     = (float*)d_out;

    const int n_nodes = in_sizes[0] - 1;     // row_ptr has n_nodes+1 entries
    const long long threads = (long long)n_nodes * 64;
    const int block = 256;
    const int grid  = (int)((threads + block - 1) / block);

    gcn_csr_agg<<<grid, block, 0, stream>>>(row_ptr, col_idx, feat, deg, out, n_nodes);
}

// Round 5
// 137.738 us; speedup vs baseline: 1.0628x; 1.0628x over previous
//
#include <hip/hip_runtime.h>
#include <hip/hip_fp16.h>

// GCN-style symmetric-normalized CSR aggregation.
// out[d][f] = sum_{e in [row_ptr[d], row_ptr[d+1])} feat[col_idx[e]][f] * rsqrt(deg[d]*deg[col_idx[e]])
//
// Round-5 structure: the gather is throughput-bound on the L2-miss path
// (feat working set 25.6MB vs 4MiB/XCD L2 -> ~55% miss). So we halve the
// gathered bytes: pass 1 converts feat fp32->fp16 into d_ws (12.8MB), pass 2
// gathers 128B fp16 rows and accumulates in fp32.
//
// Mapping (pass 2): one wave per destination row; 4 lane-groups of 16 = 4 edge
// slots, 4-way unrolled => 16 edges in flight (round-3 sweet spot; 32 was a
// measured regression - queue-capacity bound, extra slots are waste).
// Lane k of a group loads 4 halves (8B) at feature cols 4k..4k+3 => output
// layout identical to the fp32 version. Clamp out-of-range slots to the last
// edge (dup addr -> L1 hit) with weight 0: branchless.

typedef float v4f __attribute__((ext_vector_type(4)));

#define UNROLL 4   // 4 lane-slots x 4 = 16 edges in flight

// ---------------- pass 1: fp32 -> fp16 conversion ----------------
__global__ __launch_bounds__(256) void conv_f32_to_f16(
    const float4* __restrict__ in, uint2* __restrict__ out, int n4)
{
    const int i = blockIdx.x * blockDim.x + threadIdx.x;
    if (i >= n4) return;
    const float4 f = in[i];
    union { __half2 h; unsigned u; } a, b;
    a.h = __floats2half2_rn(f.x, f.y);
    b.h = __floats2half2_rn(f.z, f.w);
    out[i] = make_uint2(a.u, b.u);
}

// ---------------- pass 2: gather + aggregate (fp16 feat) ----------------
__global__ __launch_bounds__(256) void gcn_csr_agg_h(
    const int* __restrict__ row_ptr,
    const int* __restrict__ col_idx,
    const unsigned* __restrict__ feath,   // fp16 features, row stride 128B
    const float* __restrict__ deg,
    float* __restrict__ out,
    int n_nodes)
{
    const int gtid = blockIdx.x * blockDim.x + threadIdx.x;
    const int row  = gtid >> 6;
    if (row >= n_nodes) return;
    const int lane = threadIdx.x & 63;
    const int sub  = lane >> 4;            // edge slot 0..3
    const int l16  = lane & 15;
    const int hbyte = l16 << 3;            // byte offset into fp16 row: 0..120

    const int start = row_ptr[row];
    const int end   = row_ptr[row + 1];
    const int last  = end - 1;
    const float dinv = rsqrtf(deg[row]);

    const char* hbase = (const char*)feath;

    v4f acc = {0.f, 0.f, 0.f, 0.f};

    for (int eb = start; eb < end; eb += 4 * UNROLL) {
        int   e[UNROLL];
        int   s[UNROLL];
        float d[UNROLL];
        uint2 q[UNROLL];

        // Stage 1: edge-index loads.
#pragma unroll
        for (int u = 0; u < UNROLL; ++u) {
            e[u] = eb + sub + 4 * u;
            const int c = min(e[u], last);
            s[u] = col_idx[c];
        }

        // Stage 2: degree + fp16 feature loads (16 x 8B gathers in flight).
#pragma unroll
        for (int u = 0; u < UNROLL; ++u) {
            d[u] = deg[s[u]];
            const unsigned off = ((unsigned)s[u] << 7) + hbyte;  // s*128 + lane*8
            q[u] = *reinterpret_cast<const uint2*>(hbase + off);
        }

        // Stage 3: weights + convert + accumulate (fp32).
#pragma unroll
        for (int u = 0; u < UNROLL; ++u) {
            const float w = (e[u] <= last) ? dinv * rsqrtf(d[u]) : 0.f;
            union { unsigned u32; __half2 h; } a, b;
            a.u32 = q[u].x; b.u32 = q[u].y;
            const float2 p0 = __half22float2(a.h);
            const float2 p1 = __half22float2(b.h);
            acc.x += w * p0.x;
            acc.y += w * p0.y;
            acc.z += w * p1.x;
            acc.w += w * p1.y;
        }
    }

    // Reduce across the 4 edge slots.
    acc.x += __shfl_xor(acc.x, 16); acc.y += __shfl_xor(acc.y, 16);
    acc.z += __shfl_xor(acc.z, 16); acc.w += __shfl_xor(acc.w, 16);
    acc.x += __shfl_xor(acc.x, 32); acc.y += __shfl_xor(acc.y, 32);
    acc.z += __shfl_xor(acc.z, 32); acc.w += __shfl_xor(acc.w, 32);

    if (sub == 0) {
        v4f* po = reinterpret_cast<v4f*>((char*)out + ((unsigned)row << 8) + (l16 << 4));
        __builtin_nontemporal_store(acc, po);
    }
}

// ---------------- fallback: fp32 gather (round-3 kernel) ----------------
__global__ __launch_bounds__(256) void gcn_csr_agg_f(
    const int* __restrict__ row_ptr,
    const int* __restrict__ col_idx,
    const float* __restrict__ feat,
    const float* __restrict__ deg,
    float* __restrict__ out,
    int n_nodes)
{
    const int gtid = blockIdx.x * blockDim.x + threadIdx.x;
    const int row  = gtid >> 6;
    if (row >= n_nodes) return;
    const int lane = threadIdx.x & 63;
    const int sub  = lane >> 4;
    const int fbyte = (lane & 15) << 4;

    const int start = row_ptr[row];
    const int end   = row_ptr[row + 1];
    const int last  = end - 1;
    const float dinv = rsqrtf(deg[row]);
    const char* fbase = (const char*)feat;

    v4f acc = {0.f, 0.f, 0.f, 0.f};

    for (int eb = start; eb < end; eb += 4 * UNROLL) {
        int e[UNROLL]; int s[UNROLL]; float d[UNROLL]; v4f f[UNROLL];
#pragma unroll
        for (int u = 0; u < UNROLL; ++u) {
            e[u] = eb + sub + 4 * u;
            const int c = min(e[u], last);
            s[u] = col_idx[c];
        }
#pragma unroll
        for (int u = 0; u < UNROLL; ++u) {
            d[u] = deg[s[u]];
            const unsigned off = ((unsigned)s[u] << 8) + fbyte;
            f[u] = *reinterpret_cast<const v4f*>(fbase + off);
        }
#pragma unroll
        for (int u = 0; u < UNROLL; ++u) {
            const float w = (e[u] <= last) ? dinv * rsqrtf(d[u]) : 0.f;
            acc += w * f[u];
        }
    }

    acc.x += __shfl_xor(acc.x, 16); acc.y += __shfl_xor(acc.y, 16);
    acc.z += __shfl_xor(acc.z, 16); acc.w += __shfl_xor(acc.w, 16);
    acc.x += __shfl_xor(acc.x, 32); acc.y += __shfl_xor(acc.y, 32);
    acc.z += __shfl_xor(acc.z, 32); acc.w += __shfl_xor(acc.w, 32);

    if (sub == 0) {
        v4f* po = reinterpret_cast<v4f*>((char*)out + ((unsigned)row << 8) + fbyte);
        __builtin_nontemporal_store(acc, po);
    }
}

extern "C" void kernel_launch(void* const* d_in, const int* in_sizes, int n_in,
                              void* d_out, int out_size, void* d_ws, size_t ws_size,
                              hipStream_t stream) {
    const int*   row_ptr = (const int*)d_in[0];
    const int*   col_idx = (const int*)d_in[1];
    const float* feat    = (const float*)d_in[2];
    const float* deg     = (const float*)d_in[3];
    float*       out     = (float*)d_out;

    const int n_nodes = in_sizes[0] - 1;
    const int n_feat_elems = in_sizes[2];            // n_nodes * 64
    const size_t h_bytes = (size_t)n_feat_elems * 2; // fp16 copy size

    const long long threads = (long long)n_nodes * 64;
    const int block = 256;
    const int grid  = (int)((threads + block - 1) / block);

    if (ws_size >= h_bytes) {
        // pass 1: feat -> fp16 in workspace (re-run every call; ws is re-poisoned)
        const int n4 = n_feat_elems >> 2;
        const int cgrid = (n4 + block - 1) / block;
        conv_f32_to_f16<<<cgrid, block, 0, stream>>>(
            (const float4*)feat, (uint2*)d_ws, n4);
        // pass 2: gather from fp16
        gcn_csr_agg_h<<<grid, block, 0, stream>>>(
            row_ptr, col_idx, (const unsigned*)d_ws, deg, out, n_nodes);
    } else {
        gcn_csr_agg_f<<<grid, block, 0, stream>>>(
            row_ptr, col_idx, feat, deg, out, n_nodes);
    }
}

// Round 6
// 130.253 us; speedup vs baseline: 1.1239x; 1.0575x over previous
//
#include <hip/hip_runtime.h>
#include <hip/hip_fp16.h>

// GCN-style symmetric-normalized CSR aggregation.
// out[d][f] = sum_e feat[col_idx[e]][f] * rsqrt(deg[d]*deg[col_idx[e]])
//
// Round-6 theory: bound is VMEM *instruction* throughput (TA address
// processing), not bytes (halving FETCH in r5 bought only 10%). So minimize
// VMEM instructions per edge:
//   pass 1: feath[s][f] = fp16( feat[s][f] * rsqrt(deg[s]) )  -- weight folded,
//           eliminating ALL per-edge deg loads + rsqrts. 12.8 MB in d_ws.
//   pass 2: one wave per dest row. 8 slots x 8 lanes; lane k of a slot loads
//           16B (8 halves) of the row => ONE load inst covers 8 edges.
//           col_idx read coalesced: 1 inst per 64 edges (lane i ->
//           col_idx[start+i]), distributed to slots via __shfl.
//           Epilogue: reduce across slots (xor 8/16/32), scale by
//           rsqrt(deg[row]), nontemporal store.
// Per 16 edges: ~2.3 VMEM insts (was 12).

typedef float    v4f __attribute__((ext_vector_type(4)));
typedef unsigned v4u __attribute__((ext_vector_type(4)));

// ---------------- pass 1: fold rsqrt(deg[src]) and convert to fp16 ----------
__global__ __launch_bounds__(256) void conv_fold(
    const float4* __restrict__ in, const float* __restrict__ deg,
    uint2* __restrict__ out, int n4)
{
    const int i = blockIdx.x * blockDim.x + threadIdx.x;
    if (i >= n4) return;
    const float w = rsqrtf(deg[i >> 4]);   // 16 float4 per 64-float row
    const float4 f = in[i];
    union { __half2 h; unsigned u; } a, b;
    a.h = __floats2half2_rn(f.x * w, f.y * w);
    b.h = __floats2half2_rn(f.z * w, f.w * w);
    out[i] = make_uint2(a.u, b.u);
}

// ---------------- pass 2: gather + aggregate --------------------------------
__global__ __launch_bounds__(256) void gcn_gather(
    const int* __restrict__ row_ptr,
    const int* __restrict__ col_idx,
    const unsigned* __restrict__ feath,   // fp16, weight-folded, 128B rows
    const float* __restrict__ deg,
    float* __restrict__ out,
    int n_nodes)
{
    const int gtid = blockIdx.x * blockDim.x + threadIdx.x;
    const int row  = gtid >> 6;
    if (row >= n_nodes) return;
    const int lane = threadIdx.x & 63;
    const int slot = lane >> 3;        // edge slot 0..7
    const int k    = lane & 7;         // 16B chunk within row
    const int kb   = k << 4;

    const int start = row_ptr[row];
    const int end   = row_ptr[row + 1];
    const int deg_r = end - start;
    const char* hbase = (const char*)feath;

    float acc[8] = {0.f, 0.f, 0.f, 0.f, 0.f, 0.f, 0.f, 0.f};

    for (int base = 0; base < deg_r; base += 64) {
        const int nrem = min(deg_r - base, 64);
        // 1 coalesced inst: 64 edge indices (tail lanes clamp-dup the last).
        const int cidx = col_idx[start + base + min(lane, nrem - 1)];
        const int nt = (nrem + 7) >> 3;          // 8-edge steps
        for (int t = 0; t < nt; t += 2) {
            const int j0  = t * 8 + slot;
            const int j1  = j0 + 8;
            const int jj0 = min(j0, nrem - 1);
            const int jj1 = min(j1, nrem - 1);
            const int s0  = __shfl(cidx, jj0);
            const int s1  = __shfl(cidx, jj1);
            // 2 insts cover 16 edges (8 rows each, 16B/lane).
            const v4u q0 = *reinterpret_cast<const v4u*>(hbase + (((unsigned)s0) << 7) + kb);
            const v4u q1 = *reinterpret_cast<const v4u*>(hbase + (((unsigned)s1) << 7) + kb);
            const float w0 = (j0 < nrem) ? 1.f : 0.f;
            const float w1 = (j1 < nrem) ? 1.f : 0.f;
#pragma unroll
            for (int p = 0; p < 4; ++p) {
                union { unsigned u; __half2 h; } c0, c1;
                c0.u = q0[p]; c1.u = q1[p];
                const float2 f0 = __half22float2(c0.h);
                const float2 f1 = __half22float2(c1.h);
                acc[2 * p]     += w0 * f0.x + w1 * f1.x;
                acc[2 * p + 1] += w0 * f0.y + w1 * f1.y;
            }
        }
    }

    // Reduce across the 8 slots (lane bits 3,4,5).
#pragma unroll
    for (int m = 8; m <= 32; m <<= 1) {
#pragma unroll
        for (int i = 0; i < 8; ++i) acc[i] += __shfl_xor(acc[i], m);
    }

    if (slot == 0) {
        const float dinv = rsqrtf(deg[row]);   // deg clamped >= 1 by setup
        v4f lo = {acc[0] * dinv, acc[1] * dinv, acc[2] * dinv, acc[3] * dinv};
        v4f hi = {acc[4] * dinv, acc[5] * dinv, acc[6] * dinv, acc[7] * dinv};
        char* po = (char*)out + (((unsigned)row) << 8) + (k << 5);
        __builtin_nontemporal_store(lo, reinterpret_cast<v4f*>(po));
        __builtin_nontemporal_store(hi, reinterpret_cast<v4f*>(po + 16));
    }
}

// ---------------- fallback: fp32 gather (round-3 kernel) --------------------
__global__ __launch_bounds__(256) void gcn_csr_agg_f(
    const int* __restrict__ row_ptr,
    const int* __restrict__ col_idx,
    const float* __restrict__ feat,
    const float* __restrict__ deg,
    float* __restrict__ out,
    int n_nodes)
{
    const int gtid = blockIdx.x * blockDim.x + threadIdx.x;
    const int row  = gtid >> 6;
    if (row >= n_nodes) return;
    const int lane = threadIdx.x & 63;
    const int sub  = lane >> 4;
    const int fbyte = (lane & 15) << 4;

    const int start = row_ptr[row];
    const int end   = row_ptr[row + 1];
    const int last  = end - 1;
    const float dinv = rsqrtf(deg[row]);
    const char* fbase = (const char*)feat;

    v4f acc = {0.f, 0.f, 0.f, 0.f};

    for (int eb = start; eb < end; eb += 16) {
        int e[4]; int s[4]; float d[4]; v4f f[4];
#pragma unroll
        for (int u = 0; u < 4; ++u) {
            e[u] = eb + sub + 4 * u;
            const int c = min(e[u], last);
            s[u] = col_idx[c];
        }
#pragma unroll
        for (int u = 0; u < 4; ++u) {
            d[u] = deg[s[u]];
            const unsigned off = ((unsigned)s[u] << 8) + fbyte;
            f[u] = *reinterpret_cast<const v4f*>(fbase + off);
        }
#pragma unroll
        for (int u = 0; u < 4; ++u) {
            const float w = (e[u] <= last) ? dinv * rsqrtf(d[u]) : 0.f;
            acc += w * f[u];
        }
    }

    acc.x += __shfl_xor(acc.x, 16); acc.y += __shfl_xor(acc.y, 16);
    acc.z += __shfl_xor(acc.z, 16); acc.w += __shfl_xor(acc.w, 16);
    acc.x += __shfl_xor(acc.x, 32); acc.y += __shfl_xor(acc.y, 32);
    acc.z += __shfl_xor(acc.z, 32); acc.w += __shfl_xor(acc.w, 32);

    if (sub == 0) {
        v4f* po = reinterpret_cast<v4f*>((char*)out + ((unsigned)row << 8) + fbyte);
        __builtin_nontemporal_store(acc, po);
    }
}

extern "C" void kernel_launch(void* const* d_in, const int* in_sizes, int n_in,
                              void* d_out, int out_size, void* d_ws, size_t ws_size,
                              hipStream_t stream) {
    const int*   row_ptr = (const int*)d_in[0];
    const int*   col_idx = (const int*)d_in[1];
    const float* feat    = (const float*)d_in[2];
    const float* deg     = (const float*)d_in[3];
    float*       out     = (float*)d_out;

    const int n_nodes = in_sizes[0] - 1;
    const int n_feat_elems = in_sizes[2];            // n_nodes * 64
    const size_t h_bytes = (size_t)n_feat_elems * 2; // fp16 copy size

    const long long threads = (long long)n_nodes * 64;
    const int block = 256;
    const int grid  = (int)((threads + block - 1) / block);

    if (ws_size >= h_bytes) {
        const int n4 = n_feat_elems >> 2;
        const int cgrid = (n4 + block - 1) / block;
        conv_fold<<<cgrid, block, 0, stream>>>(
            (const float4*)feat, deg, (uint2*)d_ws, n4);
        gcn_gather<<<grid, block, 0, stream>>>(
            row_ptr, col_idx, (const unsigned*)d_ws, deg, out, n_nodes);
    } else {
        gcn_csr_agg_f<<<grid, block, 0, stream>>>(
            row_ptr, col_idx, feat, deg, out, n_nodes);
    }
}